// Round 11
// baseline (58.605 us; speedup 1.0000x reference)
//
#include <hip/hip_runtime.h>
#include <math.h>

typedef float f32x4 __attribute__((ext_vector_type(4)));
typedef _Float16 f16;
typedef f16 f16x8 __attribute__((ext_vector_type(8)));
typedef unsigned int u32;
typedef u32 u32x2 __attribute__((ext_vector_type(2)));

#define BB 4096
#define TT 200
#define DD 32
#define H1 80
#define H2 40
#define SLAB_W 104     // f16 per slab row: 96 used + 8 pad -> 208B stride
#define LOG2E 1.44269504f

// packed tables (f32, pre-scaled by -log2(e)) + W2 fragment table (f16, -log2(e))
__device__ __align__(16) float g_BCj[DD * H1];   // -log2e*(B-C)[k][j]
__device__ __align__(16) float g_Dj [DD * H1];   // -log2e*D[k][j]
__device__ __align__(16) float g_ACj[DD * H1];   // -log2e*(A+C)[k][j]
// W2 frags: lane l, elem e of group g=(kt*3+n) holds -log2e*W2[kt*32+(l>>4)*8+e][n*16+(l&15)]
__device__ __align__(16) f16 g_w2h[9 * 64 * 8];

// raw v_exp_f32 = 2^x (1 trans op, no ln2 mul — args are pre-scaled)
__device__ __forceinline__ float exp2_raw(float x) {
    float r;
    asm("v_exp_f32 %0, %1" : "=v"(r) : "v"(x));
    return r;
}
// sigmoid with pre-negated-scaled arg: a = -log2e*z  ->  sigmoid(z)
__device__ __forceinline__ float sig_pre(float a) {
    return __builtin_amdgcn_rcpf(1.f + exp2_raw(a));
}

__global__ void pack_kernel(const float* __restrict__ W1, const float* __restrict__ W2) {
    int idx = blockIdx.x * 256 + threadIdx.x;
    if (idx < DD * H1) {
        int kk = idx / H1, j = idx % H1;
        g_BCj[idx] = -LOG2E * (W1[(32 + kk) * H1 + j] - W1[(64 + kk) * H1 + j]);
        g_Dj [idx] = -LOG2E * W1[(96 + kk) * H1 + j];
        g_ACj[idx] = -LOG2E * (W1[kk * H1 + j] + W1[(64 + kk) * H1 + j]);
        return;
    }
    idx -= DD * H1;
    if (idx < 9 * 64 * 8) {                       // W2 fragments, padded K=96 N=48
        int e = idx & 7, l = (idx >> 3) & 63, g = idx >> 9;
        int kt = g / 3, n = g % 3;
        int j   = kt * 32 + (l >> 4) * 8 + e;     // K index (H1 dim)
        int col = n * 16 + (l & 15);              // N index (H2 dim)
        float v = (j < H1 && col < H2) ? W2[j * H2 + col] : 0.f;
        g_w2h[idx] = (f16)(-LOG2E * v);
    }
}

// R11: TWO waves per row (even/odd m-tiles), grid 2048 = 8 blocks/CU -> 2x waves.
// Each wave: same single-slab 2-stage pipeline on 6-7 tiles. qp shared (barrier 1),
// lgt shared (barrier 2), softmax redundant, output writes split by sub-wave.
// exp2 pre-scaling: all sigmoid args arrive as -log2e*z; logits arrive as
// log2e*logit (softmax done base-2 — mathematically identical).
// NO min-waves launch_bounds (R5: 64-VGPR cap + spill).
__global__ __launch_bounds__(256) void din_mfma(
    const float* __restrict__ q, const float* __restrict__ k, const int* __restrict__ mask,
    const float* __restrict__ Wq, const float* __restrict__ bq, const float* __restrict__ alpha,
    const float* __restrict__ b1, const float* __restrict__ b2, const float* __restrict__ Wf,
    float* __restrict__ out)
{
    const int tid = threadIdx.x;
    const int wid = tid >> 6, l = tid & 63;
    const int l15 = l & 15, lg4 = l >> 4;
    const int r   = wid >> 1, s = wid & 1;        // row-in-block, sub-wave
    const int b   = (blockIdx.x << 1) | r;        // this row

    __shared__ __align__(16) f16   slab[4][16][SLAB_W];   // per-wave sg slab
    __shared__ __align__(16) float qp_s[2][DD];
    __shared__ __align__(16) float u_s[2][H1];
    __shared__ __align__(16) float lgt[2][208];

    // W2 fragments -> registers (lane-contiguous 16B loads, L2-cached)
    f16x8 W2r[9];
    #pragma unroll
    for (int g = 0; g < 9; ++g) W2r[g] = *(const f16x8*)(g_w2h + (g * 64 + l) * 8);

    // hoist mask row loads (redundant per sub-wave; softmax is redundant too)
    const int* mrow = mask + (size_t)b * TT;
    int mk0 = mrow[l];
    int mk1 = mrow[64 + l];
    int mk2 = mrow[128 + l];
    int mk3 = (l < 8) ? mrow[192 + l] : 1;

    // ---- phase 0a (sub-wave 0 of each row): qp = prelu(q[b] @ Wq + bq) ----
    if (s == 0 && l < DD) {
        const float* qr = q + (size_t)b * DD;
        float acc = bq[l];
        #pragma unroll
        for (int e = 0; e < DD; ++e) acc += qr[e] * Wq[e * DD + l];
        float a = alpha[l];
        qp_s[r][l] = acc >= 0.f ? acc : a * acc;
    }
    // zero own slab pad cols j=80..95 (kt=2 reads them; W2 frags are 0 there)
    {
        u32* z0 = (u32*)slab[wid];                // 52 u32 per row
        #pragma unroll
        for (int i = 0; i < 2; ++i) {
            int idx = i * 64 + l;                 // 0..127 = 16 rows x 8 u32
            z0[(idx >> 3) * 52 + 40 + (idx & 7)] = 0u;
        }
    }

    __syncthreads();   // barrier 1: qp visible to both sub-waves of the row
    const float* qp = qp_s[r];

    // ---- phase 0b: u'[j] = -log2e*b1[j] + qp.(A+C)'[:,j]  (tables pre-scaled) ----
    #pragma unroll
    for (int i = 0; i < 2; ++i) {
        int c = i * 64 + l;
        if (c < H1) {
            float acc = -LOG2E * b1[c];
            #pragma unroll
            for (int d = 0; d < DD; ++d) acc += qp[d] * g_ACj[d * H1 + c];
            u_s[r][c] = acc;                      // redundant same-value write: benign
        }
    }
    // L1 A-operand frags (W1', pre-scaled): [j=n*16+l15][d=lg4*8+e], f16
    f16x8 Bh[5];
    #pragma unroll
    for (int n = 0; n < 5; ++n) {
        #pragma unroll
        for (int e = 0; e < 8; ++e) {
            int kidx = lg4 * 8 + e;
            int j = n * 16 + l15;
            Bh[n][e] = (f16)(g_BCj[kidx * H1 + j] + qp[kidx] * g_Dj[kidx * H1 + j]);
        }
    }
    // per-lane b2/Wf quads (transposed L2): lane owns H2 cols c0..c0+3
    f32x4 b2r[3], wfr[3];
    #pragma unroll
    for (int n = 0; n < 3; ++n) {
        int c0 = n * 16 + lg4 * 4;
        if (c0 + 3 < H2) {
            f32x4 bv = *(const f32x4*)(b2 + c0);
            f32x4 wv = *(const f32x4*)(Wf + c0);
            #pragma unroll
            for (int e = 0; e < 4; ++e) { bv[e] *= -LOG2E; wv[e] *= LOG2E; }
            b2r[n] = bv;
            wfr[n] = wv;
        } else {
            b2r[n] = (f32x4){0.f, 0.f, 0.f, 0.f};
            wfr[n] = (f32x4){0.f, 0.f, 0.f, 0.f};
        }
    }
    // u -> registers (acc init quads); reads this wave's own u_s writes
    f32x4 ur[5];
    #pragma unroll
    for (int n = 0; n < 5; ++n) ur[n] = *(const f32x4*)(&u_s[r][n * 16 + lg4 * 4]);

    // ---- main loop: tiles m = s, s+2, ..., single-slab 2-stage pipeline ----
    const float* kb = k + (size_t)b * (TT * DD);
    f16 (*ws)[SLAB_W] = slab[wid];
    float* lg = lgt[r];

    f32x4 x0, x1;
    auto loadk = [&](int m) {
        int t = m * 16 + l15; if (t > TT - 1) t = TT - 1;
        const f32x4* kr = (const f32x4*)(kb + t * DD + lg4 * 8);
        x0 = kr[0]; x1 = kr[1];
    };

    auto l1_full = [&](int nload) {
        f16x8 Ah;
        #pragma unroll
        for (int e = 0; e < 4; ++e) {
            Ah[e]     = (f16)x0[e];
            Ah[e + 4] = (f16)x1[e];
        }
        if (nload >= 0) loadk(nload);
        #pragma unroll
        for (int n = 0; n < 5; ++n) {
            int j0 = n * 16 + lg4 * 4;
            f32x4 acc = ur[n];                    // -log2e*(u + ...) via MFMA below
            acc = __builtin_amdgcn_mfma_f32_16x16x32_f16(Bh[n], Ah, acc, 0, 0, 0);
            auto p01 = __builtin_amdgcn_cvt_pkrtz(sig_pre(acc[0]), sig_pre(acc[1]));
            auto p23 = __builtin_amdgcn_cvt_pkrtz(sig_pre(acc[2]), sig_pre(acc[3]));
            u32x2 w;
            w[0] = __builtin_bit_cast(u32, p01);
            w[1] = __builtin_bit_cast(u32, p23);
            *(u32x2*)(&ws[l15][j0]) = w;
        }
    };

    // body(m): sh reads (tile m, in-order LDS) -> L1(m+2) overlap -> L2(m)
    auto body = [&](int m) {
        f16x8 sh0 = *(const f16x8*)(&ws[l15][0 * 32 + lg4 * 8]);
        f16x8 sh1 = *(const f16x8*)(&ws[l15][1 * 32 + lg4 * 8]);
        f16x8 sh2 = *(const f16x8*)(&ws[l15][2 * 32 + lg4 * 8]);

        if (m + 2 < 13) l1_full(m + 4 < 13 ? m + 4 : -1);

        f32x4 a0 = {0.f,0.f,0.f,0.f}, a1 = {0.f,0.f,0.f,0.f}, a2 = {0.f,0.f,0.f,0.f};
        #pragma unroll
        for (int kt = 0; kt < 3; ++kt) {
            f16x8 sh = (kt == 0) ? sh0 : (kt == 1) ? sh1 : sh2;
            a0 = __builtin_amdgcn_mfma_f32_16x16x32_f16(W2r[kt * 3 + 0], sh, a0, 0, 0, 0);
            a1 = __builtin_amdgcn_mfma_f32_16x16x32_f16(W2r[kt * 3 + 1], sh, a1, 0, 0, 0);
            a2 = __builtin_amdgcn_mfma_f32_16x16x32_f16(W2r[kt * 3 + 2], sh, a2, 0, 0, 0);
        }

        // balanced-tree dot: per n a 4-term tree, then 3-way sum -> 1.4427*logit
        float pn[3];
        #pragma unroll
        for (int n = 0; n < 3; ++n) {
            f32x4 av = (n == 0) ? a0 : (n == 1) ? a1 : a2;
            float t0 = wfr[n][0] * sig_pre(av[0] + b2r[n][0]);
            float t1 = wfr[n][1] * sig_pre(av[1] + b2r[n][1]);
            float t2 = wfr[n][2] * sig_pre(av[2] + b2r[n][2]);
            float t3 = wfr[n][3] * sig_pre(av[3] + b2r[n][3]);
            pn[n] = (t0 + t1) + (t2 + t3);
        }
        float p = (pn[0] + pn[1]) + pn[2];
        p += __shfl_xor(p, 16);
        p += __shfl_xor(p, 32);
        if (l < 16) lg[m * 16 + l15] = p;
    };

    // prologue: x <- tile s; L1(s) -> slab; prefetch tile s+2
    loadk(s);
    l1_full(s + 2 < 13 ? s + 2 : -1);
    for (int m = s; m < 13; m += 2) body(m);

    __syncthreads();   // barrier 2: lgt complete from both sub-waves

    // ---- masked softmax over t<200 (base-2; logits pre-scaled by log2e) ----
    const float NEG = -4294967295.0f;
    float v0 = lg[l];        if (mk0 == 0) v0 = NEG;
    float v1 = lg[64 + l];   if (mk1 == 0) v1 = NEG;
    float v2 = lg[128 + l];  if (mk2 == 0) v2 = NEG;
    float v3 = -8589934590.0f;
    if (l < 8) { v3 = lg[192 + l]; if (mk3 == 0) v3 = NEG; }

    float mx = fmaxf(fmaxf(v0, v1), fmaxf(v2, v3));
    #pragma unroll
    for (int off = 32; off; off >>= 1) mx = fmaxf(mx, __shfl_xor(mx, off));

    float e0 = exp2_raw(v0 - mx), e1 = exp2_raw(v1 - mx);
    float e2 = exp2_raw(v2 - mx), e3 = exp2_raw(v3 - mx);  // pad lanes underflow to 0
    float ssum = (e0 + e1) + (e2 + e3);
    #pragma unroll
    for (int off = 32; off; off >>= 1) ssum += __shfl_xor(ssum, off);

    float* orow = out + (size_t)b * TT;
    if (s == 0) {
        orow[l]      = e0 / ssum;
        orow[64 + l] = e1 / ssum;
    } else {
        orow[128 + l] = e2 / ssum;
        if (l < 8) orow[192 + l] = e3 / ssum;
    }
}

extern "C" void kernel_launch(void* const* d_in, const int* in_sizes, int n_in,
                              void* d_out, int out_size, void* d_ws, size_t ws_size,
                              hipStream_t stream) {
    const float* q     = (const float*)d_in[0];
    const float* k     = (const float*)d_in[1];
    // d_in[2] = v : unused by the reference output
    const int*   mask  = (const int*)d_in[3];
    const float* Wq    = (const float*)d_in[4];
    const float* bq    = (const float*)d_in[5];
    const float* alpha = (const float*)d_in[6];
    const float* W1    = (const float*)d_in[7];
    const float* b1    = (const float*)d_in[8];
    const float* W2    = (const float*)d_in[9];
    const float* b2    = (const float*)d_in[10];
    const float* Wf    = (const float*)d_in[11];
    // d_in[12] = bf : dropped (softmax is shift-invariant, incl. all-masked rows)
    float* out = (float*)d_out;

    hipLaunchKernelGGL(pack_kernel, dim3((DD * H1 + 9 * 64 * 8 + 255) / 256), dim3(256),
                       0, stream, W1, W2);
    hipLaunchKernelGGL(din_mfma, dim3(BB / 2), dim3(256), 0, stream,
                       q, k, mask, Wq, bq, alpha, b1, b2, Wf, out);
}

// Round 12
// 51.681 us; speedup vs baseline: 1.1340x; 1.1340x over previous
//
#include <hip/hip_runtime.h>
#include <math.h>

typedef float f32x4 __attribute__((ext_vector_type(4)));
typedef _Float16 f16;
typedef f16 f16x8 __attribute__((ext_vector_type(8)));
typedef unsigned int u32;
typedef u32 u32x2 __attribute__((ext_vector_type(2)));

#define BB 4096
#define TT 200
#define DD 32
#define H1 80
#define H2 40
#define SLAB_W 104     // f16 per slab row: 96 used + 8 pad -> 208B stride
#define LOG2E 1.44269504f

// packed tables (f32, pre-scaled by -log2(e)) + W2 fragment table (f16, -log2(e))
__device__ __align__(16) float g_BCj[DD * H1];   // -log2e*(B-C)[k][j]
__device__ __align__(16) float g_Dj [DD * H1];   // -log2e*D[k][j]
__device__ __align__(16) float g_ACj[DD * H1];   // -log2e*(A+C)[k][j]
__device__ __align__(16) f16 g_w2h[9 * 64 * 8];  // -log2e*W2 frags

// raw v_exp_f32 = 2^x (args pre-scaled, no ln2 mul)
__device__ __forceinline__ float exp2_raw(float x) {
    float r;
    asm("v_exp_f32 %0, %1" : "=v"(r) : "v"(x));
    return r;
}
// a = -log2e*z  ->  sigmoid(z)
__device__ __forceinline__ float sig_pre(float a) {
    return __builtin_amdgcn_rcpf(1.f + exp2_raw(a));
}

__global__ void pack_kernel(const float* __restrict__ W1, const float* __restrict__ W2) {
    int idx = blockIdx.x * 256 + threadIdx.x;
    if (idx < DD * H1) {
        int kk = idx / H1, j = idx % H1;
        g_BCj[idx] = -LOG2E * (W1[(32 + kk) * H1 + j] - W1[(64 + kk) * H1 + j]);
        g_Dj [idx] = -LOG2E * W1[(96 + kk) * H1 + j];
        g_ACj[idx] = -LOG2E * (W1[kk * H1 + j] + W1[(64 + kk) * H1 + j]);
        return;
    }
    idx -= DD * H1;
    if (idx < 9 * 64 * 8) {                       // W2 fragments, padded K=96 N=48
        int e = idx & 7, l = (idx >> 3) & 63, g = idx >> 9;
        int kt = g / 3, n = g % 3;
        int j   = kt * 32 + (l >> 4) * 8 + e;     // K index (H1 dim)
        int col = n * 16 + (l & 15);              // N index (H2 dim)
        float v = (j < H1 && col < H2) ? W2[j * H2 + col] : 0.f;
        g_w2h[idx] = (f16)(-LOG2E * v);
    }
}

// R12: one row per WAVE (grid 1024, all-resident), TWO-TILE-WIDE body:
// {sh(m), sh(m+1)} -> {L1(m+2)->bufA, L1(m+3)->bufB} -> {L2(m), L2(m+1)}.
// Doubles the independent work inside every stall window (MFMA/trans/LDS
// latency) of a wave. W2 frags in LDS + u in LDS to hold VGPR <= 128
// (R5 cliff; R10 showed W2 regs<->LDS is perf-neutral).
// exp2 pre-scaling throughout (R11, exact). NO min-waves launch_bounds.
__global__ __launch_bounds__(256) void din_mfma(
    const float* __restrict__ q, const float* __restrict__ k, const int* __restrict__ mask,
    const float* __restrict__ Wq, const float* __restrict__ bq, const float* __restrict__ alpha,
    const float* __restrict__ b1, const float* __restrict__ b2, const float* __restrict__ Wf,
    float* __restrict__ out)
{
    const int tid = threadIdx.x;
    const int wid = tid >> 6, l = tid & 63;
    const int l15 = l & 15, lg4 = l >> 4;
    const int b   = (blockIdx.x << 2) | wid;      // this wave's batch row

    __shared__ __align__(16) f16   slab[4][2][16][SLAB_W]; // per-wave even/odd slabs
    __shared__ __align__(16) f16   w2h_s[9 * 64 * 8];      // W2 frags (block-shared)
    __shared__ __align__(16) float u_s[4][H1];
    __shared__ __align__(16) float lgt[4][208];
    // qp aliased into lgt (lgt written only in main loop; qp dead by then)
    float* qp = lgt[wid];

    // ---- stage W2 frags -> LDS (only cross-wave dependency) ----
    {
        const u32* src = (const u32*)g_w2h;       // 2304 u32 = 9 * 256
        u32* dst = (u32*)w2h_s;
        #pragma unroll
        for (int i = 0; i < 9; ++i) dst[i * 256 + tid] = src[i * 256 + tid];
    }

    // hoist mask row loads
    const int* mrow = mask + (size_t)b * TT;
    int mk0 = mrow[l];
    int mk1 = mrow[64 + l];
    int mk2 = mrow[128 + l];
    int mk3 = (l < 8) ? mrow[192 + l] : 1;

    // ---- phase 0a (per wave): qp = prelu(q[b] @ Wq + bq) ----
    if (l < DD) {
        const float* qr = q + (size_t)b * DD;
        float acc = bq[l];
        #pragma unroll
        for (int e = 0; e < DD; ++e) acc += qr[e] * Wq[e * DD + l];
        float a = alpha[l];
        qp[l] = acc >= 0.f ? acc : a * acc;
    }
    // zero pad cols j=80..95 of both buffers (kt=2 reads them; W2 frags 0 there)
    {
        u32* z0 = (u32*)slab[wid][0];
        u32* z1 = (u32*)slab[wid][1];
        #pragma unroll
        for (int i = 0; i < 2; ++i) {
            int idx = i * 64 + l;                 // 0..127 = 16 rows x 8 u32
            int off = (idx >> 3) * 52 + 40 + (idx & 7);
            z0[off] = 0u;
            z1[off] = 0u;
        }
    }

    // ---- phase 0b: u'[j] = -log2e*b1[j] + qp.(A+C)'[:,j] (pre-scaled tables) ----
    #pragma unroll
    for (int i = 0; i < 2; ++i) {
        int c = i * 64 + l;
        if (c < H1) {
            float acc = -LOG2E * b1[c];
            #pragma unroll
            for (int d = 0; d < DD; ++d) acc += qp[d] * g_ACj[d * H1 + c];
            u_s[wid][c] = acc;
        }
    }
    // L1 A-operand frags (W1', pre-scaled): [j=n*16+l15][d=lg4*8+e]
    f16x8 Bh[5];
    #pragma unroll
    for (int n = 0; n < 5; ++n) {
        #pragma unroll
        for (int e = 0; e < 8; ++e) {
            int kidx = lg4 * 8 + e;
            int j = n * 16 + l15;
            Bh[n][e] = (f16)(g_BCj[kidx * H1 + j] + qp[kidx] * g_Dj[kidx * H1 + j]);
        }
    }
    // per-lane b2/Wf quads (transposed L2), pre-scaled
    f32x4 b2r[3], wfr[3];
    #pragma unroll
    for (int n = 0; n < 3; ++n) {
        int c0 = n * 16 + lg4 * 4;
        if (c0 + 3 < H2) {
            f32x4 bv = *(const f32x4*)(b2 + c0);
            f32x4 wv = *(const f32x4*)(Wf + c0);
            #pragma unroll
            for (int e = 0; e < 4; ++e) { bv[e] *= -LOG2E; wv[e] *= LOG2E; }
            b2r[n] = bv;
            wfr[n] = wv;
        } else {
            b2r[n] = (f32x4){0.f, 0.f, 0.f, 0.f};
            wfr[n] = (f32x4){0.f, 0.f, 0.f, 0.f};
        }
    }

    __syncthreads();   // only barrier: w2h_s visible to all waves

    // ---- main loop: 2-tile-wide body over 13 m-tiles ----
    const float* kb = k + (size_t)b * (TT * DD);
    f16 (*ws0)[SLAB_W] = slab[wid][0];            // even tiles
    f16 (*ws1)[SLAB_W] = slab[wid][1];            // odd tiles
    float* lg = lgt[wid];

    f32x4 x0, x1, x2, x3;                         // even pair / odd pair k regs
    auto loadk = [&](int m, f32x4& a, f32x4& c) {
        int t = m * 16 + l15; if (t > TT - 1) t = TT - 1;
        const f32x4* kr = (const f32x4*)(kb + t * DD + lg4 * 8);
        a = kr[0]; c = kr[1];
    };

    // L1 for the tile in (xa,xb) -> wbuf; optional prefetch nload into (xa,xb)
    auto l1_full = [&](f16 (*wbuf)[SLAB_W], f32x4& xa, f32x4& xb, int nload) {
        f16x8 Ah;
        #pragma unroll
        for (int e = 0; e < 4; ++e) {
            Ah[e]     = (f16)xa[e];
            Ah[e + 4] = (f16)xb[e];
        }
        if (nload >= 0) loadk(nload, xa, xb);
        #pragma unroll
        for (int n = 0; n < 5; ++n) {
            int j0 = n * 16 + lg4 * 4;
            f32x4 acc = *(const f32x4*)(&u_s[wid][j0]);   // u' from LDS
            acc = __builtin_amdgcn_mfma_f32_16x16x32_f16(Bh[n], Ah, acc, 0, 0, 0);
            auto p01 = __builtin_amdgcn_cvt_pkrtz(sig_pre(acc[0]), sig_pre(acc[1]));
            auto p23 = __builtin_amdgcn_cvt_pkrtz(sig_pre(acc[2]), sig_pre(acc[3]));
            u32x2 w;
            w[0] = __builtin_bit_cast(u32, p01);
            w[1] = __builtin_bit_cast(u32, p23);
            *(u32x2*)(&wbuf[l15][j0]) = w;
        }
    };

    // L2 (transposed) for one tile given its sh frags; store 1.4427*logit
    auto l2_one = [&](int m, f16x8 sh0, f16x8 sh1, f16x8 sh2) {
        f32x4 a0 = {0.f,0.f,0.f,0.f}, a1 = {0.f,0.f,0.f,0.f}, a2 = {0.f,0.f,0.f,0.f};
        #pragma unroll
        for (int kt = 0; kt < 3; ++kt) {
            f16x8 w0 = *(const f16x8*)(w2h_s + ((kt * 3 + 0) * 64 + l) * 8);
            f16x8 w1 = *(const f16x8*)(w2h_s + ((kt * 3 + 1) * 64 + l) * 8);
            f16x8 w2 = *(const f16x8*)(w2h_s + ((kt * 3 + 2) * 64 + l) * 8);
            f16x8 sh = (kt == 0) ? sh0 : (kt == 1) ? sh1 : sh2;
            a0 = __builtin_amdgcn_mfma_f32_16x16x32_f16(w0, sh, a0, 0, 0, 0);
            a1 = __builtin_amdgcn_mfma_f32_16x16x32_f16(w1, sh, a1, 0, 0, 0);
            a2 = __builtin_amdgcn_mfma_f32_16x16x32_f16(w2, sh, a2, 0, 0, 0);
        }
        float pn[3];
        #pragma unroll
        for (int n = 0; n < 3; ++n) {
            f32x4 av = (n == 0) ? a0 : (n == 1) ? a1 : a2;
            float t0 = wfr[n][0] * sig_pre(av[0] + b2r[n][0]);
            float t1 = wfr[n][1] * sig_pre(av[1] + b2r[n][1]);
            float t2 = wfr[n][2] * sig_pre(av[2] + b2r[n][2]);
            float t3 = wfr[n][3] * sig_pre(av[3] + b2r[n][3]);
            pn[n] = (t0 + t1) + (t2 + t3);
        }
        float p = (pn[0] + pn[1]) + pn[2];
        p += __shfl_xor(p, 16);
        p += __shfl_xor(p, 32);
        if (l < 16) lg[m * 16 + l15] = p;
    };

    // prologue: tiles 0 (->A) and 1 (->B); x01/x23 then hold tiles 2/3
    loadk(0, x0, x1);
    loadk(1, x2, x3);
    l1_full(ws0, x0, x1, 2);
    l1_full(ws1, x2, x3, 3);

    for (int m = 0; m < 13; m += 2) {
        // sh reads first (in-order LDS: before this body's overwrites)
        f16x8 sA0 = *(const f16x8*)(&ws0[l15][0 * 32 + lg4 * 8]);
        f16x8 sA1 = *(const f16x8*)(&ws0[l15][1 * 32 + lg4 * 8]);
        f16x8 sA2 = *(const f16x8*)(&ws0[l15][2 * 32 + lg4 * 8]);
        f16x8 sB0, sB1, sB2;
        if (m + 1 < 13) {
            sB0 = *(const f16x8*)(&ws1[l15][0 * 32 + lg4 * 8]);
            sB1 = *(const f16x8*)(&ws1[l15][1 * 32 + lg4 * 8]);
            sB2 = *(const f16x8*)(&ws1[l15][2 * 32 + lg4 * 8]);
        }
        // two independent L1 streams fill the L2s' stall windows (and vice versa)
        if (m + 2 < 13) l1_full(ws0, x0, x1, (m + 4 < 13) ? m + 4 : -1);
        if (m + 3 < 13) l1_full(ws1, x2, x3, (m + 5 < 13) ? m + 5 : -1);
        l2_one(m, sA0, sA1, sA2);
        if (m + 1 < 13) l2_one(m + 1, sB0, sB1, sB2);
    }

    // ---- per-wave masked softmax over t<200 (base-2; logits pre-scaled) ----
    const float NEG = -4294967295.0f;
    float v0 = lg[l];        if (mk0 == 0) v0 = NEG;
    float v1 = lg[64 + l];   if (mk1 == 0) v1 = NEG;
    float v2 = lg[128 + l];  if (mk2 == 0) v2 = NEG;
    float v3 = -8589934590.0f;
    if (l < 8) { v3 = lg[192 + l]; if (mk3 == 0) v3 = NEG; }

    float mx = fmaxf(fmaxf(v0, v1), fmaxf(v2, v3));
    #pragma unroll
    for (int off = 32; off; off >>= 1) mx = fmaxf(mx, __shfl_xor(mx, off));

    float e0 = exp2_raw(v0 - mx), e1 = exp2_raw(v1 - mx);
    float e2 = exp2_raw(v2 - mx), e3 = exp2_raw(v3 - mx);
    float ssum = (e0 + e1) + (e2 + e3);
    #pragma unroll
    for (int off = 32; off; off >>= 1) ssum += __shfl_xor(ssum, off);

    float* orow = out + (size_t)b * TT;
    orow[l]       = e0 / ssum;
    orow[64 + l]  = e1 / ssum;
    orow[128 + l] = e2 / ssum;
    if (l < 8) orow[192 + l] = e3 / ssum;
}

extern "C" void kernel_launch(void* const* d_in, const int* in_sizes, int n_in,
                              void* d_out, int out_size, void* d_ws, size_t ws_size,
                              hipStream_t stream) {
    const float* q     = (const float*)d_in[0];
    const float* k     = (const float*)d_in[1];
    // d_in[2] = v : unused by the reference output
    const int*   mask  = (const int*)d_in[3];
    const float* Wq    = (const float*)d_in[4];
    const float* bq    = (const float*)d_in[5];
    const float* alpha = (const float*)d_in[6];
    const float* W1    = (const float*)d_in[7];
    const float* b1    = (const float*)d_in[8];
    const float* W2    = (const float*)d_in[9];
    const float* b2    = (const float*)d_in[10];
    const float* Wf    = (const float*)d_in[11];
    // d_in[12] = bf : dropped (softmax is shift-invariant, incl. all-masked rows)
    float* out = (float*)d_out;

    hipLaunchKernelGGL(pack_kernel, dim3((DD * H1 + 9 * 64 * 8 + 255) / 256), dim3(256),
                       0, stream, W1, W2);
    hipLaunchKernelGGL(din_mfma, dim3(BB / 4), dim3(256), 0, stream,
                       q, k, mask, Wq, bq, alpha, b1, b2, Wf, out);
}

// Round 13
// 51.005 us; speedup vs baseline: 1.1490x; 1.0133x over previous
//
#include <hip/hip_runtime.h>
#include <math.h>

typedef float f32x4 __attribute__((ext_vector_type(4)));
typedef _Float16 f16;
typedef f16 f16x8 __attribute__((ext_vector_type(8)));
typedef unsigned int u32;
typedef u32 u32x2 __attribute__((ext_vector_type(2)));

#define BB 4096
#define TT 200
#define DD 32
#define H1 80
#define H2 40
#define SLAB_W 104     // f16 per slab row: 96 used + 8 pad -> 208B stride
#define LOG2E 1.44269504f

// ALL tables pre-arranged by pack_kernel into per-lane-contiguous layouts so the
// din prologue is pure 16B vector loads (the old layouts caused 80+ scalar
// strided L2-latency-bound loads = most of the ~10us prologue).
__device__ __align__(16) float g_wqt[DD * DD];        // [col][e] = Wq[e][col]
__device__ __align__(16) float g_act[H1 * DD];        // [c][d] = -log2e*(A+C)[d][c]
__device__ __align__(16) float g_bcf[5 * 64 * 8];     // [n][l][e] = -log2e*(B-C)[kidx][j]
__device__ __align__(16) float g_df [5 * 64 * 8];     // [n][l][e] = -log2e*D[kidx][j]
__device__ __align__(16) f16   g_w2h[9 * 64 * 8];     // -log2e*W2 frags [kt*3+n][l][e]

// raw v_exp_f32 = 2^x (args pre-scaled, no ln2 mul)
__device__ __forceinline__ float exp2_raw(float x) {
    float r;
    asm("v_exp_f32 %0, %1" : "=v"(r) : "v"(x));
    return r;
}
// a = -log2e*z  ->  sigmoid(z)
__device__ __forceinline__ float sig_pre(float a) {
    return __builtin_amdgcn_rcpf(1.f + exp2_raw(a));
}

__global__ void pack_kernel(const float* __restrict__ W1, const float* __restrict__ W2,
                            const float* __restrict__ Wq) {
    int idx = blockIdx.x * 256 + threadIdx.x;           // 13312 total = 52 blocks
    if (idx < DD * DD) {                                // g_wqt: [col][e]
        int col = idx / DD, e = idx % DD;
        g_wqt[idx] = Wq[e * DD + col];
        return;
    }
    idx -= DD * DD;
    if (idx < H1 * DD) {                                // g_act: [c][d]
        int c = idx / DD, d = idx % DD;
        g_act[idx] = -LOG2E * (W1[d * H1 + c] + W1[(64 + d) * H1 + c]);
        return;
    }
    idx -= H1 * DD;
    if (idx < 5 * 64 * 8) {                             // g_bcf / g_df frag layout
        int e = idx & 7, l = (idx >> 3) & 63, n = idx >> 9;
        int kidx = (l >> 4) * 8 + e;
        int j = n * 16 + (l & 15);
        g_bcf[idx] = -LOG2E * (W1[(32 + kidx) * H1 + j] - W1[(64 + kidx) * H1 + j]);
        g_df [idx] = -LOG2E * W1[(96 + kidx) * H1 + j];
        return;
    }
    idx -= 5 * 64 * 8;
    if (idx < 9 * 64 * 8) {                             // W2 frags, padded K=96 N=48
        int e = idx & 7, l = (idx >> 3) & 63, g = idx >> 9;
        int kt = g / 3, n = g % 3;
        int j   = kt * 32 + (l >> 4) * 8 + e;
        int col = n * 16 + (l & 15);
        float v = (j < H1 && col < H2) ? W2[j * H2 + col] : 0.f;
        g_w2h[idx] = (f16)(-LOG2E * v);
    }
}

// one row per WAVE; barrier-free; single-buffered slab (per-wave in-order LDS:
// body's sh-reads precede l1_full's overwrite). W2 frags + u + b2/Wf in regs.
// exp2 pre-scaling throughout (base-2 softmax — mathematically identical).
// NO min-waves launch_bounds (R5: 64-VGPR cap + spill).
__global__ __launch_bounds__(256) void din_mfma(
    const float* __restrict__ q, const float* __restrict__ k, const int* __restrict__ mask,
    const float* __restrict__ bq, const float* __restrict__ alpha,
    const float* __restrict__ b1, const float* __restrict__ b2, const float* __restrict__ Wf,
    float* __restrict__ out)
{
    const int tid = threadIdx.x;
    const int wid = tid >> 6, l = tid & 63;
    const int l15 = l & 15, lg4 = l >> 4;
    const int b   = (blockIdx.x << 2) | wid;      // this wave's batch row

    __shared__ __align__(16) f16   slab[4][16][SLAB_W];   // per-wave sg slab
    __shared__ __align__(16) float u_s[4][H1];
    __shared__ __align__(16) float lgt[4][208];
    float* qp = lgt[wid];                         // alias: qp dead before lgt written

    // W2 fragments -> registers (9 x 16B contiguous)
    f16x8 W2r[9];
    #pragma unroll
    for (int g = 0; g < 9; ++g) W2r[g] = *(const f16x8*)(g_w2h + (g * 64 + l) * 8);

    // hoist mask row loads
    const int* mrow = mask + (size_t)b * TT;
    int mk0 = mrow[l];
    int mk1 = mrow[64 + l];
    int mk2 = mrow[128 + l];
    int mk3 = (l < 8) ? mrow[192 + l] : 1;

    // ---- phase 0a: qp = prelu(q[b] @ Wq + bq) — all vector loads ----
    if (l < DD) {
        const f32x4* qv = (const f32x4*)(q + (size_t)b * DD);
        const f32x4* wv = (const f32x4*)(g_wqt + l * DD);   // transposed row, contig
        float acc = bq[l];
        #pragma unroll
        for (int i = 0; i < 8; ++i) {
            f32x4 a = qv[i], w = wv[i];
            acc += (a[0] * w[0] + a[1] * w[1]) + (a[2] * w[2] + a[3] * w[3]);
        }
        float al = alpha[l];
        qp[l] = acc >= 0.f ? acc : al * acc;
    }
    // zero slab pad cols j=80..95 (kt=2 A-frags read them; W2 frags are 0 there)
    {
        u32* z0 = (u32*)slab[wid];                // 52 u32 per row
        #pragma unroll
        for (int i = 0; i < 2; ++i) {
            int idx = i * 64 + l;
            z0[(idx >> 3) * 52 + 40 + (idx & 7)] = 0u;
        }
    }

    // qp -> registers (full row for u; slice for Bh). Same-wave LDS: in-order.
    f32x4 qp4[8];
    #pragma unroll
    for (int j = 0; j < 8; ++j) qp4[j] = *(const f32x4*)(&qp[j * 4]);
    f32x4 qpa = *(const f32x4*)(&qp[lg4 * 8]);
    f32x4 qpb = *(const f32x4*)(&qp[lg4 * 8 + 4]);

    // ---- phase 0b: u'[c] = -log2e*b1[c] + qp.(A+C)'[:,c] — vector loads ----
    #pragma unroll
    for (int i = 0; i < 2; ++i) {
        int c = i * 64 + l;
        if (c < H1) {
            const f32x4* av = (const f32x4*)(g_act + c * DD);   // transposed, contig
            float acc = -LOG2E * b1[c];
            #pragma unroll
            for (int j = 0; j < 8; ++j) {
                f32x4 a = av[j], p = qp4[j];
                acc += (a[0] * p[0] + a[1] * p[1]) + (a[2] * p[2] + a[3] * p[3]);
            }
            u_s[wid][c] = acc;
        }
    }
    // L1 A-frags (W1', pre-scaled) from frag-layout tables — 20 vector loads
    f16x8 Bh[5];
    #pragma unroll
    for (int n = 0; n < 5; ++n) {
        const f32x4* bv = (const f32x4*)(g_bcf + (n * 64 + l) * 8);
        const f32x4* dv = (const f32x4*)(g_df  + (n * 64 + l) * 8);
        f32x4 b0 = bv[0], b1v = bv[1], d0 = dv[0], d1 = dv[1];
        #pragma unroll
        for (int e = 0; e < 4; ++e) {
            Bh[n][e]     = (f16)(b0[e]  + qpa[e] * d0[e]);
            Bh[n][e + 4] = (f16)(b1v[e] + qpb[e] * d1[e]);
        }
    }
    // per-lane b2/Wf quads (transposed L2), pre-scaled
    f32x4 b2r[3], wfr[3];
    #pragma unroll
    for (int n = 0; n < 3; ++n) {
        int c0 = n * 16 + lg4 * 4;
        if (c0 + 3 < H2) {
            f32x4 bv = *(const f32x4*)(b2 + c0);
            f32x4 wv = *(const f32x4*)(Wf + c0);
            #pragma unroll
            for (int e = 0; e < 4; ++e) { bv[e] *= -LOG2E; wv[e] *= LOG2E; }
            b2r[n] = bv;
            wfr[n] = wv;
        } else {
            b2r[n] = (f32x4){0.f, 0.f, 0.f, 0.f};
            wfr[n] = (f32x4){0.f, 0.f, 0.f, 0.f};
        }
    }
    // u -> registers (acc init quads); same-wave in-order LDS
    f32x4 ur[5];
    #pragma unroll
    for (int n = 0; n < 5; ++n) ur[n] = *(const f32x4*)(&u_s[wid][n * 16 + lg4 * 4]);

    // ---- main loop: 13 m-tiles, 2-stage pipeline on a single slab buffer ----
    const float* kb = k + (size_t)b * (TT * DD);
    f16 (*ws)[SLAB_W] = slab[wid];
    float* lg = lgt[wid];

    f32x4 x0, x1;
    auto loadk = [&](int m) {
        int t = m * 16 + l15; if (t > TT - 1) t = TT - 1;
        const f32x4* kr = (const f32x4*)(kb + t * DD + lg4 * 8);
        x0 = kr[0]; x1 = kr[1];
    };

    auto l1_full = [&](int nload) {
        f16x8 Ah;
        #pragma unroll
        for (int e = 0; e < 4; ++e) {
            Ah[e]     = (f16)x0[e];
            Ah[e + 4] = (f16)x1[e];
        }
        if (nload >= 0) loadk(nload);
        #pragma unroll
        for (int n = 0; n < 5; ++n) {
            int j0 = n * 16 + lg4 * 4;
            f32x4 acc = ur[n];
            acc = __builtin_amdgcn_mfma_f32_16x16x32_f16(Bh[n], Ah, acc, 0, 0, 0);
            auto p01 = __builtin_amdgcn_cvt_pkrtz(sig_pre(acc[0]), sig_pre(acc[1]));
            auto p23 = __builtin_amdgcn_cvt_pkrtz(sig_pre(acc[2]), sig_pre(acc[3]));
            u32x2 w;
            w[0] = __builtin_bit_cast(u32, p01);
            w[1] = __builtin_bit_cast(u32, p23);
            *(u32x2*)(&ws[l15][j0]) = w;
        }
    };

    // body(m): sh reads (tile m) -> L1(m+1) overlap -> L2(m); transposed L2,
    // lane holds 4 H2-cols of one t (=l15) -> 2-shuffle reduce
    auto body = [&](int m) {
        f16x8 sh0 = *(const f16x8*)(&ws[l15][0 * 32 + lg4 * 8]);
        f16x8 sh1 = *(const f16x8*)(&ws[l15][1 * 32 + lg4 * 8]);
        f16x8 sh2 = *(const f16x8*)(&ws[l15][2 * 32 + lg4 * 8]);

        if (m < 12) l1_full(m < 11 ? m + 2 : -1);

        f32x4 a0 = {0.f,0.f,0.f,0.f}, a1 = {0.f,0.f,0.f,0.f}, a2 = {0.f,0.f,0.f,0.f};
        #pragma unroll
        for (int kt = 0; kt < 3; ++kt) {
            f16x8 sh = (kt == 0) ? sh0 : (kt == 1) ? sh1 : sh2;
            a0 = __builtin_amdgcn_mfma_f32_16x16x32_f16(W2r[kt * 3 + 0], sh, a0, 0, 0, 0);
            a1 = __builtin_amdgcn_mfma_f32_16x16x32_f16(W2r[kt * 3 + 1], sh, a1, 0, 0, 0);
            a2 = __builtin_amdgcn_mfma_f32_16x16x32_f16(W2r[kt * 3 + 2], sh, a2, 0, 0, 0);
        }

        float pn[3];
        #pragma unroll
        for (int n = 0; n < 3; ++n) {
            f32x4 av = (n == 0) ? a0 : (n == 1) ? a1 : a2;
            float t0 = wfr[n][0] * sig_pre(av[0] + b2r[n][0]);
            float t1 = wfr[n][1] * sig_pre(av[1] + b2r[n][1]);
            float t2 = wfr[n][2] * sig_pre(av[2] + b2r[n][2]);
            float t3 = wfr[n][3] * sig_pre(av[3] + b2r[n][3]);
            pn[n] = (t0 + t1) + (t2 + t3);
        }
        float p = (pn[0] + pn[1]) + pn[2];
        p += __shfl_xor(p, 16);
        p += __shfl_xor(p, 32);
        if (l < 16) lg[m * 16 + l15] = p;
    };

    loadk(0);
    l1_full(1);
    for (int m = 0; m < 13; ++m) body(m);

    // ---- per-wave masked softmax over t<200 (base-2; logits pre-scaled) ----
    const float NEG = -4294967295.0f;
    float v0 = lg[l];        if (mk0 == 0) v0 = NEG;
    float v1 = lg[64 + l];   if (mk1 == 0) v1 = NEG;
    float v2 = lg[128 + l];  if (mk2 == 0) v2 = NEG;
    float v3 = -8589934590.0f;
    if (l < 8) { v3 = lg[192 + l]; if (mk3 == 0) v3 = NEG; }

    float mx = fmaxf(fmaxf(v0, v1), fmaxf(v2, v3));
    #pragma unroll
    for (int off = 32; off; off >>= 1) mx = fmaxf(mx, __shfl_xor(mx, off));

    float e0 = exp2_raw(v0 - mx), e1 = exp2_raw(v1 - mx);
    float e2 = exp2_raw(v2 - mx), e3 = exp2_raw(v3 - mx);
    float ssum = (e0 + e1) + (e2 + e3);
    #pragma unroll
    for (int off = 32; off; off >>= 1) ssum += __shfl_xor(ssum, off);

    float* orow = out + (size_t)b * TT;
    orow[l]       = e0 / ssum;
    orow[64 + l]  = e1 / ssum;
    orow[128 + l] = e2 / ssum;
    if (l < 8) orow[192 + l] = e3 / ssum;
}

extern "C" void kernel_launch(void* const* d_in, const int* in_sizes, int n_in,
                              void* d_out, int out_size, void* d_ws, size_t ws_size,
                              hipStream_t stream) {
    const float* q     = (const float*)d_in[0];
    const float* k     = (const float*)d_in[1];
    // d_in[2] = v : unused by the reference output
    const int*   mask  = (const int*)d_in[3];
    const float* Wq    = (const float*)d_in[4];
    const float* bq    = (const float*)d_in[5];
    const float* alpha = (const float*)d_in[6];
    const float* W1    = (const float*)d_in[7];
    const float* b1    = (const float*)d_in[8];
    const float* W2    = (const float*)d_in[9];
    const float* b2    = (const float*)d_in[10];
    const float* Wf    = (const float*)d_in[11];
    // d_in[12] = bf : dropped (softmax is shift-invariant, incl. all-masked rows)
    float* out = (float*)d_out;

    // pack covers 1024+2560+2560(x2 tables share idx)+4608 -> 13312 threads
    hipLaunchKernelGGL(pack_kernel, dim3(52), dim3(256), 0, stream, W1, W2, Wq);
    hipLaunchKernelGGL(din_mfma, dim3(BB / 4), dim3(256), 0, stream,
                       q, k, mask, bq, alpha, b1, b2, Wf, out);
}